// Round 10
// baseline (213.055 us; speedup 1.0000x reference)
//
#include <hip/hip_runtime.h>

typedef __attribute__((ext_vector_type(8))) short short8;
typedef __attribute__((ext_vector_type(4))) float f32x4;
typedef __attribute__((ext_vector_type(16))) float f32x16;

#define B_ROWS 16384

__device__ __forceinline__ float bf2f(ushort u){ return __uint_as_float(((uint)u)<<16); }
__device__ __forceinline__ ushort f2bf(float f){
  uint u = __float_as_uint(f);
  u = u + 0x7FFFu + ((u>>16)&1u);
  return (ushort)(u>>16);
}
__device__ __forceinline__ void gload_lds16(const void* g, void* l){
  __builtin_amdgcn_global_load_lds((const __attribute__((address_space(1))) unsigned*)g,
                                   (__attribute__((address_space(3))) unsigned*)l, 16, 0, 0);
}

// ---------------- combined prep kernel: bot0 + 5 weight transposes + partial+cnt zero
// grid: [0,32768) bot0; [32768,34976) transpose tiles; [34976,35041) zero partial+cnt
struct TArgs { const float* in; ushort* out; int K, N, Kp; };
struct PrepArgs {
  const float* x; const float* W0; const float* b0; ushort* act0;  // bot0
  TArgs t[5];
  float* partial;   // 16384 partials + 64 counters
};

__global__ __launch_bounds__(256) void prep(PrepArgs a)
{
  const int idx = blockIdx.x;
  const int tid = threadIdx.x;
  __shared__ float tile[32][33];

  if (idx < 32768){                       // ---- bot0: (B,13)@(13,512)+b, relu -> bf16
    int i = idx*256 + tid;
    int b = i>>9, n = i&511;
    const float* xr = a.x + (size_t)b*13;
    float s = a.b0[n];
    #pragma unroll
    for (int k=0;k<13;k++) s += xr[k]*a.W0[k*512+n];
    a.act0[i] = f2bf(fmaxf(s,0.f));
    return;
  }
  if (idx >= 34976){                      // ---- zero partial buffer + finisher counters
    int j = (idx-34976)*256 + tid;
    if (j < 16448) a.partial[j] = 0.f;
    return;
  }
  // ---- transpose tiles: bW1(16x8), bW2(8x4), tW0(16x32), tW1(32x32), tW2(32x16)
  int t = idx - 32768, s, kx, ny;
  if (t < 128)              { s=0; kx=t&15; ny=t>>4; }
  else if ((t-=128) < 32)   { s=1; kx=t&7 ; ny=t>>3; }
  else if ((t-=32) < 512)   { s=2; kx=t&15; ny=t>>4; }
  else if ((t-=512) < 1024) { s=3; kx=t&31; ny=t>>5; }
  else { t-=1024;             s=4; kx=t&31; ny=t>>5; }
  TArgs ta = a.t[s];
  int k0 = kx*32, n0 = ny*32;
  const int c = tid & 31, r8 = tid >> 5;
  #pragma unroll
  for (int p=0;p<4;p++){
    int k = k0 + r8 + p*8;
    tile[r8+p*8][c] = (k < ta.K) ? ta.in[(size_t)k*ta.N + n0 + c] : 0.f;
  }
  __syncthreads();
  #pragma unroll
  for (int p=0;p<4;p++){
    int n = n0 + r8 + p*8;
    ta.out[(size_t)n*ta.Kp + k0 + c] = f2bf(tile[c][r8+p*8]);
  }
}

// ---------------- fused bottom layers 1+2, 32-row blocks (2 blocks/CU):
// act0(32x512)@W1t^T -> act1(32x256, LDS only) -> @W2t^T (W2t read from global, L2-hot)
// -> x(32x128) into R cols [0,128). 4 waves; phase-1 tiles XOR-swizzled (row&7)<<4.
__global__ __launch_bounds__(256) void bot12(const ushort* __restrict__ act0,
    const ushort* __restrict__ W1t, const float* __restrict__ b1,
    const ushort* __restrict__ W2t, const float* __restrict__ b2,
    ushort* __restrict__ R)
{
  // LDS (72KB): lA[2]=[0,8K) ; lB[2]=[8K,72K). act1 (32x264 ushorts=16896B) reuses [0,16896).
  __shared__ __align__(16) char smem[73728];
  const int tid = threadIdx.x;
  const int wave = tid>>6, lane = tid&63;
  const int lr = lane&15, lg = lane>>4;
  const int bm = blockIdx.x*32;

  auto stage = [&](int buf, int kt){
    {                                // A: act0 tile 32x64 (4KB), 128B rows, 1 load/thread
      uint lin = (uint)tid*16u;
      uint row = lin>>7, scol = (lin&127u) ^ ((row&7u)<<4);
      gload_lds16((const char*)act0 + (((size_t)(bm+row)*512 + (uint)kt*64u)<<1) + scol,
                  smem + (buf?4096:0) + lin);
    }
    #pragma unroll
    for (int c=0;c<8;c++){           // B: W1t tile 256x64 (32KB), 128B rows
      uint lin = (uint)tid*16u + (uint)c*4096u;
      uint row = lin>>7, scol = (lin&127u) ^ ((row&7u)<<4);
      gload_lds16((const char*)W1t + (((size_t)row*512 + (uint)kt*64u)<<1) + scol,
                  smem + 8192 + (buf?32768:0) + lin);
    }
  };

  f32x4 acc[2][4];
  #pragma unroll
  for (int m=0;m<2;m++)
    #pragma unroll
    for (int n=0;n<4;n++)
      #pragma unroll
      for (int j=0;j<4;j++) acc[m][n][j] = 0.f;

  stage(0,0);
  int cur = 0;
  for (int t=0;t<8;t++){
    stage(cur^1, (t+1<8) ? t+1 : 0);   // dead tail stage keeps vmcnt uniform
    asm volatile("s_waitcnt vmcnt(9)" ::: "memory");
    __builtin_amdgcn_s_barrier();
    asm volatile("" ::: "memory");
    const char* lAc = smem + (cur?4096:0);
    const char* lBc = smem + 8192 + (cur?32768:0);
    #pragma unroll
    for (int kk2=0;kk2<2;kk2++){
      short8 af[2], bfr[4];
      #pragma unroll
      for (int m=0;m<2;m++){
        uint row = (uint)(m*16+lr);
        uint l = row*128u + (uint)kk2*64u + (uint)lg*16u;
        af[m] = *(const short8*)(lAc + (l ^ ((row&7u)<<4)));
      }
      #pragma unroll
      for (int n=0;n<4;n++){
        uint row = (uint)(wave*64 + n*16+lr);
        uint l = row*128u + (uint)kk2*64u + (uint)lg*16u;
        bfr[n] = *(const short8*)(lBc + (l ^ ((row&7u)<<4)));
      }
      #pragma unroll
      for (int m=0;m<2;m++)
        #pragma unroll
        for (int n=0;n<4;n++)
          acc[m][n] = __builtin_amdgcn_mfma_f32_16x16x32_bf16(af[m], bfr[n], acc[m][n], 0,0,0);
    }
    asm volatile("" ::: "memory");
    __builtin_amdgcn_s_barrier();
    cur ^= 1;
  }
  asm volatile("s_waitcnt vmcnt(0)" ::: "memory");   // drain tail before LDS reuse
  __syncthreads();

  // act1 -> LDS (relu + b1), padded stride 264 ushorts
  ushort* a1 = (ushort*)smem;
  #pragma unroll
  for (int n=0;n<4;n++){
    int col = wave*64 + n*16 + lr;
    float bv = b1[col];
    #pragma unroll
    for (int m=0;m<2;m++)
      #pragma unroll
      for (int j=0;j<4;j++){
        int row = m*16 + lg*4 + j;
        a1[(uint)row*264u + (uint)col] = f2bf(fmaxf(acc[m][n][j] + bv, 0.f));
      }
  }
  __syncthreads();

  // phase 2: x(32x128) = act1(32x256) @ W2t(128x256)^T ; W2t fragments from global
  f32x4 acc2[2][2];
  #pragma unroll
  for (int m=0;m<2;m++)
    #pragma unroll
    for (int n=0;n<2;n++)
      #pragma unroll
      for (int j=0;j<4;j++) acc2[m][n][j] = 0.f;

  #pragma unroll
  for (int ks=0;ks<8;ks++){
    short8 af[2], bw[2];
    #pragma unroll
    for (int m=0;m<2;m++)
      af[m] = *(const short8*)&a1[(uint)(m*16+lr)*264u + (uint)ks*32u + (uint)lg*8u];
    #pragma unroll
    for (int n=0;n<2;n++){
      int row = wave*32 + n*16 + lr;
      bw[n] = *(const short8*)(W2t + (size_t)row*256 + ks*32 + lg*8);
    }
    #pragma unroll
    for (int m=0;m<2;m++)
      #pragma unroll
      for (int n=0;n<2;n++)
        acc2[m][n] = __builtin_amdgcn_mfma_f32_16x16x32_bf16(af[m], bw[n], acc2[m][n], 0,0,0);
  }

  #pragma unroll
  for (int n=0;n<2;n++){
    int col = wave*32 + n*16 + lr;
    float bv = b2[col];
    #pragma unroll
    for (int m=0;m<2;m++)
      #pragma unroll
      for (int j=0;j<4;j++){
        int row = bm + m*16 + lg*4 + j;
        R[(size_t)row*512 + col] = f2bf(fmaxf(acc2[m][n][j] + bv, 0.f));
      }
  }
}

// ---------------- 256xBN deep-pipelined GEMM (8 phases / 2 K-tiles, counted vmcnt, swizzled LDS)
// FUSE: final-layer dot fused + finisher block applies sigmoid (replaces sigm kernel).
template<int BN, bool FUSE>
__global__ __launch_bounds__(512, 2) void gemm256(const ushort* __restrict__ A,
    const ushort* __restrict__ Bt, const float* __restrict__ bias,
    ushort* __restrict__ C, int K, int ldc,
    const float* __restrict__ w3, float* __restrict__ partial,
    int* __restrict__ cnt, const float* __restrict__ b3, float* __restrict__ outp)
{
  constexpr int  NF = BN/128;
  constexpr int  LB = BN/128;
  constexpr uint BR = (uint)BN*32u;
  constexpr uint BUFSZ = 16384u + 2u*BR;
  __shared__ __align__(16) ushort lds[2*BUFSZ];

  const int tid = threadIdx.x;
  const int wave = tid>>6, lane = tid&63;
  const uint wm = (uint)(wave>>2), wn = (uint)(wave&3);
  const uint lc = (uint)(lane&31), hi = (uint)(lane>>5);
  const int bm = blockIdx.x*256, bn = blockIdx.y*BN;
  const int nt = K>>6, niter = nt>>1;

  f32x16 acc[4][NF];
  #pragma unroll
  for (int m=0;m<4;m++)
    #pragma unroll
    for (int n=0;n<NF;n++)
      #pragma unroll
      for (int j=0;j<16;j++) acc[m][n][j] = 0.f;

  short8 bfr[2][NF];

#define STAGE(MAT, KH, TILE, SBUF) do{                                          \
    int kt_ = (TILE);                                                           \
    int ktc_ = (kt_ < nt) ? kt_ : 0;                                            \
    const ushort* gb_ = (MAT) ? Bt : A;                                         \
    const uint ro_ = (MAT) ? (uint)bn : (uint)bm;                               \
    const uint rb_ = (uint)(SBUF)*BUFSZ + ((MAT) ? (16384u + (uint)(KH)*BR)     \
                                                 : ((uint)(KH)*8192u));         \
    const int nl_ = (MAT) ? LB : 2;                                             \
    _Pragma("unroll")                                                           \
    for (int j_=0; j_<nl_; ++j_){                                               \
      uint lin_ = (uint)tid*16u + (uint)j_*8192u;                               \
      uint src_ = lin_ ^ (((lin_>>7)&3u)<<4);                                   \
      uint row_ = src_>>6, colb_ = src_&63u;                                    \
      const char* g_ = (const char*)gb_ +                                       \
        (((size_t)(ro_+row_)*(size_t)K + (size_t)ktc_*64 + (KH)*32)<<1) + colb_;\
      gload_lds16(g_, (char*)lds + (size_t)rb_*2 + lin_);                       \
    }                                                                           \
  }while(0)

#define PHASE(CBUF, KKH, MH, BLOAD, SMAT, SKH, STILE, SBUF, CKPT) do{           \
    const uint ab_ = (uint)(CBUF)*BUFSZ + (uint)(KKH)*8192u;                    \
    short8 af_[2][2];                                                           \
    _Pragma("unroll")                                                           \
    for (int mfl_=0; mfl_<2; ++mfl_){                                           \
      uint r_ = wm*128u + ((uint)(MH)*2u+(uint)mfl_)*32u + lc;                  \
      _Pragma("unroll")                                                         \
      for (int k2_=0; k2_<2; ++k2_){                                            \
        uint l_ = r_*64u + hi*16u + (uint)k2_*32u;                              \
        af_[mfl_][k2_] = *(const short8*)((const char*)lds + (size_t)ab_*2      \
                                   + (l_ ^ (((l_>>7)&3u)<<4)));                 \
      }                                                                         \
    }                                                                           \
    if (BLOAD){                                                                 \
      const uint bb_ = (uint)(CBUF)*BUFSZ + 16384u + (uint)(KKH)*BR;            \
      _Pragma("unroll")                                                         \
      for (int nf_=0; nf_<NF; ++nf_){                                           \
        uint r_ = wn*(uint)(BN/4) + (uint)nf_*32u + lc;                         \
        _Pragma("unroll")                                                       \
        for (int k2_=0; k2_<2; ++k2_){                                          \
          uint l_ = r_*64u + hi*16u + (uint)k2_*32u;                            \
          bfr[k2_][nf_] = *(const short8*)((const char*)lds + (size_t)bb_*2     \
                                     + (l_ ^ (((l_>>7)&3u)<<4)));               \
        }                                                                       \
      }                                                                         \
    }                                                                           \
    STAGE(SMAT, SKH, STILE, SBUF);                                              \
    asm volatile("" ::: "memory");                                              \
    __builtin_amdgcn_s_barrier();                                               \
    asm volatile("" ::: "memory");                                              \
    __builtin_amdgcn_s_setprio(1);                                              \
    _Pragma("unroll")                                                           \
    for (int mfl_=0; mfl_<2; ++mfl_)                                            \
      _Pragma("unroll")                                                         \
      for (int nf_=0; nf_<NF; ++nf_)                                            \
        _Pragma("unroll")                                                       \
        for (int k2_=0; k2_<2; ++k2_)                                           \
          acc[(MH)*2+mfl_][nf_] = __builtin_amdgcn_mfma_f32_32x32x16_bf16(      \
              af_[mfl_][k2_], bfr[k2_][nf_], acc[(MH)*2+mfl_][nf_], 0,0,0);     \
    __builtin_amdgcn_s_setprio(0);                                              \
    if (CKPT){                                                                  \
      if constexpr (LB==2) asm volatile("s_waitcnt vmcnt(8)" ::: "memory");     \
      else                 asm volatile("s_waitcnt vmcnt(6)" ::: "memory");     \
    }                                                                           \
    asm volatile("" ::: "memory");                                              \
    __builtin_amdgcn_s_barrier();                                               \
  }while(0)

  STAGE(0,0,0,0); STAGE(1,0,0,0); STAGE(0,1,0,0); STAGE(1,1,0,0);
  STAGE(0,0,1,1); STAGE(1,0,1,1);
  if constexpr (LB==2) asm volatile("s_waitcnt vmcnt(4)" ::: "memory");
  else                 asm volatile("s_waitcnt vmcnt(3)" ::: "memory");
  asm volatile("" ::: "memory");
  __builtin_amdgcn_s_barrier();

  for (int i=0; i<niter; ++i){
    const int O  = 2*i+1;
    const int E2 = 2*i+2;
    const int O2 = 2*i+3;
    PHASE(0,0,0,true , 0,1,O ,1, false);
    PHASE(0,0,1,false, 1,1,O ,1, true );
    PHASE(0,1,0,true , 0,0,E2,0, false);
    PHASE(0,1,1,false, 1,0,E2,0, true );
    PHASE(1,0,0,true , 0,1,E2,0, false);
    PHASE(1,0,1,false, 1,1,E2,0, true );
    PHASE(1,1,0,true , 0,0,O2,1, false);
    PHASE(1,1,1,false, 1,0,O2,1, true );
  }
#undef PHASE
#undef STAGE

  if constexpr (FUSE){
    // final-layer fusion (NF==1): v = relu(acc+b)*w3[col]; reduce over lc; atomicAdd
    int col = bn + (int)wn*(BN/4) + (int)lc;
    float bv = bias[col];
    float wv = w3[col];
    #pragma unroll
    for (int mf=0; mf<4; ++mf){
      #pragma unroll
      for (int reg=0; reg<16; ++reg){
        float v = fmaxf(acc[mf][0][reg] + bv, 0.f) * wv;
        #pragma unroll
        for (int off=1; off<32; off<<=1) v += __shfl_xor(v, off);
        if (lc == 0){
          int row = bm + (int)wm*128 + mf*32 + (reg&3) + 8*(reg>>2) + 4*(int)hi;
          atomicAdd(&partial[row], v);
        }
      }
    }
    // finisher: 4th block for this bm applies sigmoid for rows [bm,bm+256)
    __threadfence();
    volatile int* flag = (volatile int*)lds;
    if (tid == 0){
      int old = atomicAdd(cnt + blockIdx.x, 1);
      *flag = (old == 3) ? 1 : 0;
    }
    __syncthreads();
    if (*flag){
      float bb = b3[0];
      for (int r = tid; r < 256; r += 512){
        float h = atomicAdd(&partial[bm + r], 0.f) + bb;   // coherent read
        float p = 1.f/(1.f + expf(-h));
        outp[bm + r] = fminf(fmaxf(p, 0.f), 1.f);
      }
    }
  } else {
    #pragma unroll
    for (int nf=0; nf<NF; ++nf){
      int col = bn + (int)wn*(BN/4) + nf*32 + (int)lc;
      float bv = bias[col];
      #pragma unroll
      for (int mf=0; mf<4; ++mf){
        #pragma unroll
        for (int reg=0; reg<16; ++reg){
          int row = bm + (int)wm*128 + mf*32 + (reg&3) + 8*(reg>>2) + 4*(int)hi;
          float v = acc[mf][nf][reg] + bv;
          C[(size_t)row*ldc + col] = f2bf(fmaxf(v, 0.f));
        }
      }
    }
  }
}

// ---------------- embedding gather + pairwise interaction, in-place on R (B x 512 bf16)
__global__ __launch_bounds__(256) void interact(const int* __restrict__ idx,
    const float* __restrict__ emb, ushort* __restrict__ R)
{
  __shared__ __align__(16) ushort Tl[4][32][136];
  const int w = threadIdx.x>>6, l = threadIdx.x&63;
  const int b = blockIdx.x*4 + w;
  ushort* Rrow = R + (size_t)b*512;

  uint xv = ((const uint*)Rrow)[l];
  *(uint*)&Tl[w][0][2*l] = xv;

  int myidx = (l<26) ? idx[(size_t)l*B_ROWS + b] : 0;
  const int half = l>>5, lc = l&31;
  #pragma unroll
  for (int i=0;i<13;i++){
    const int row = 2*i + 1 + half;
    int e = __shfl(myidx, row - 1);
    const float4* rp = (const float4*)(emb + ((size_t)(row-1)*50000 + (size_t)e)*128);
    float4 v = rp[lc];
    uint2 pk;
    pk.x = (uint)f2bf(v.x) | ((uint)f2bf(v.y)<<16);
    pk.y = (uint)f2bf(v.z) | ((uint)f2bf(v.w)<<16);
    *(uint2*)&Tl[w][row][4*lc] = pk;
  }
  __syncthreads();

  f32x16 acc;
  #pragma unroll
  for (int i=0;i<16;i++) acc[i] = 0.f;
  #pragma unroll
  for (int kk=0;kk<8;kk++){
    short8 fa = *(const short8*)((const char*)&Tl[w][0][0] + (size_t)(l&31)*272 + kk*32 + (l>>5)*16);
    acc = __builtin_amdgcn_mfma_f32_32x32x16_bf16(fa, fa, acc, 0,0,0);
  }

  const int c = l&31;
  #pragma unroll
  for (int j=0;j<16;j++){
    int r = (j&3) + 8*(j>>2) + 4*(l>>5);
    if (c < r && r <= 26) Rrow[128 + r*(r-1)/2 + c] = f2bf(acc[j]);
  }
  if (l < 33) Rrow[479 + l] = 0;
}

extern "C" void kernel_launch(void* const* d_in, const int* in_sizes, int n_in,
                              void* d_out, int out_size, void* d_ws, size_t ws_size,
                              hipStream_t stream)
{
  const float* dense_x = (const float*)d_in[0];
  const int*   indices = (const int*)d_in[1];
  const float* emb     = (const float*)d_in[2];
  const float* bW0 = (const float*)d_in[3];  const float* bb0 = (const float*)d_in[4];
  const float* bW1 = (const float*)d_in[5];  const float* bb1 = (const float*)d_in[6];
  const float* bW2 = (const float*)d_in[7];  const float* bb2 = (const float*)d_in[8];
  const float* tW0 = (const float*)d_in[9];  const float* tb0 = (const float*)d_in[10];
  const float* tW1 = (const float*)d_in[11]; const float* tb1 = (const float*)d_in[12];
  const float* tW2 = (const float*)d_in[13]; const float* tb2 = (const float*)d_in[14];
  const float* tW3 = (const float*)d_in[15]; const float* tb3 = (const float*)d_in[16];
  float* out = (float*)d_out;
  const int Bn = B_ROWS;

  char* ws = (char*)d_ws;
  size_t o = 0;
  auto alloc = [&](size_t bytes)->char*{ char* r = ws + o; o += (bytes + 255) & ~(size_t)255; return r; };
  ushort* wtB1 = (ushort*)alloc(256*512*2);
  ushort* wtB2 = (ushort*)alloc(128*256*2);
  ushort* wtT0 = (ushort*)alloc(1024*512*2);
  ushort* wtT1 = (ushort*)alloc((size_t)1024*1024*2);
  ushort* wtT2 = (ushort*)alloc(512*1024*2);
  float*  partial = (float*)alloc((B_ROWS+64)*4);    // 16384 partials + 64 counters
  ushort* P    = (ushort*)alloc((size_t)Bn*512*2);
  ushort* h1   = (ushort*)alloc((size_t)Bn*1024*2);
  ushort* h2   = (ushort*)alloc((size_t)Bn*1024*2);
  int* cnt = (int*)(partial + B_ROWS);
  (void)ws_size; (void)in_sizes; (void)n_in; (void)out_size;

  // combined prep: bot0 + weight transposes + partial/cnt zeroing
  PrepArgs pa;
  pa.x = dense_x; pa.W0 = bW0; pa.b0 = bb0; pa.act0 = P;
  pa.t[0] = { bW1, wtB1, 512 , 256 , 512  };
  pa.t[1] = { bW2, wtB2, 256 , 128 , 256  };
  pa.t[2] = { tW0, wtT0, 479 , 1024, 512  };
  pa.t[3] = { tW1, wtT1, 1024, 1024, 1024 };
  pa.t[4] = { tW2, wtT2, 1024, 512 , 1024 };
  pa.partial = partial;
  prep<<<35041,256,0,stream>>>(pa);

  // fused bottom layers 1+2 (act1 LDS-only; x into R cols [0,128)); 2 blocks/CU
  bot12<<<512,256,0,stream>>>(P, wtB1, bb1, wtB2, bb2, P);

  // gather + interaction in place on R (= P)
  interact<<<Bn/4,256,0,stream>>>(indices, emb, P);

  // top MLP: deep-pipelined 256-tile GEMMs; top2 fuses final dot + sigmoid finisher
  gemm256<256,false><<<dim3(64,4),512,0,stream>>>(P,  wtT0, tb0, h1, 512 , 1024,
                                                  nullptr, nullptr, nullptr, nullptr, nullptr);
  gemm256<256,false><<<dim3(64,4),512,0,stream>>>(h1, wtT1, tb1, h2, 1024, 1024,
                                                  nullptr, nullptr, nullptr, nullptr, nullptr);
  gemm256<128,true ><<<dim3(64,4),512,0,stream>>>(h2, wtT2, tb2, nullptr, 1024, 0,
                                                  tW3, partial, cnt, tb3, out);
}

// Round 11
// 185.424 us; speedup vs baseline: 1.1490x; 1.1490x over previous
//
#include <hip/hip_runtime.h>

typedef __attribute__((ext_vector_type(8))) short short8;
typedef __attribute__((ext_vector_type(4))) float f32x4;
typedef __attribute__((ext_vector_type(16))) float f32x16;

#define B_ROWS 16384

__device__ __forceinline__ float bf2f(ushort u){ return __uint_as_float(((uint)u)<<16); }
__device__ __forceinline__ ushort f2bf(float f){
  uint u = __float_as_uint(f);
  u = u + 0x7FFFu + ((u>>16)&1u);
  return (ushort)(u>>16);
}
__device__ __forceinline__ void gload_lds16(const void* g, void* l){
  __builtin_amdgcn_global_load_lds((const __attribute__((address_space(1))) unsigned*)g,
                                   (__attribute__((address_space(3))) unsigned*)l, 16, 0, 0);
}

// ---------------- combined prep kernel: bot0 + 5 weight transposes + partial-zero
// grid: [0,32768) bot0; [32768,34976) transpose tiles; [34976,35040) zero partial
struct TArgs { const float* in; ushort* out; int K, N, Kp; };
struct PrepArgs {
  const float* x; const float* W0; const float* b0; ushort* act0;  // bot0
  TArgs t[5];
  float* partial;
};

__global__ __launch_bounds__(256) void prep(PrepArgs a)
{
  const int idx = blockIdx.x;
  const int tid = threadIdx.x;
  __shared__ float tile[32][33];

  if (idx < 32768){                       // ---- bot0: (B,13)@(13,512)+b, relu -> bf16
    int i = idx*256 + tid;
    int b = i>>9, n = i&511;
    const float* xr = a.x + (size_t)b*13;
    float s = a.b0[n];
    #pragma unroll
    for (int k=0;k<13;k++) s += xr[k]*a.W0[k*512+n];
    a.act0[i] = f2bf(fmaxf(s,0.f));
    return;
  }
  if (idx >= 34976){                      // ---- zero the final-layer partial buffer
    a.partial[(idx-34976)*256 + tid] = 0.f;
    return;
  }
  // ---- transpose tiles: bW1(16x8), bW2(8x4), tW0(16x32), tW1(32x32), tW2(32x16)
  int t = idx - 32768, s, kx, ny;
  if (t < 128)              { s=0; kx=t&15; ny=t>>4; }
  else if ((t-=128) < 32)   { s=1; kx=t&7 ; ny=t>>3; }
  else if ((t-=32) < 512)   { s=2; kx=t&15; ny=t>>4; }
  else if ((t-=512) < 1024) { s=3; kx=t&31; ny=t>>5; }
  else { t-=1024;             s=4; kx=t&31; ny=t>>5; }
  TArgs ta = a.t[s];
  int k0 = kx*32, n0 = ny*32;
  const int c = tid & 31, r8 = tid >> 5;
  #pragma unroll
  for (int p=0;p<4;p++){
    int k = k0 + r8 + p*8;
    tile[r8+p*8][c] = (k < ta.K) ? ta.in[(size_t)k*ta.N + n0 + c] : 0.f;
  }
  __syncthreads();
  #pragma unroll
  for (int p=0;p<4;p++){
    int n = n0 + r8 + p*8;
    ta.out[(size_t)n*ta.Kp + k0 + c] = f2bf(tile[c][r8+p*8]);
  }
}

// ---------------- fused bottom layers 1+2: act0(64x512)@W1t^T -> act1(64x256, LDS only)
// -> @W2t^T -> x(64x128) into R cols [0,128). 64-row blocks, 4 waves, 2 blocks/CU.
// Phase-1 LDS tiles XOR-swizzled (row&7)<<4 both sides; act1 padded stride 264.
// W2t operand lives in 32 VGPRs/lane (rows wave*32+{lr,16+lr}, k-slice lg*8) -> LDS 80KB.
__global__ __launch_bounds__(256) void bot12(const ushort* __restrict__ act0,
    const ushort* __restrict__ W1t, const float* __restrict__ b1,
    const ushort* __restrict__ W2t, const float* __restrict__ b2,
    ushort* __restrict__ R)
{
  // LDS map (bytes): lA[2]=[0,16K) ; lB[2]=[16K,80K)
  // act1 (64 x 264 ushorts = 33792B) reuses [0,33792) after phase-1 drained.
  __shared__ __align__(16) char smem[81920];
  const int tid = threadIdx.x;
  const int wave = tid>>6, lane = tid&63;
  const int lr = lane&15, lg = lane>>4;
  const int bm = blockIdx.x*64;

  // preload W2 fragments into registers (issued before stage-0; drained by first vmcnt(10))
  short8 w2r[2][8];
  #pragma unroll
  for (int n=0;n<2;n++){
    int row = wave*32 + n*16 + lr;
    #pragma unroll
    for (int ks=0;ks<8;ks++)
      w2r[n][ks] = *(const short8*)(W2t + (size_t)row*256 + ks*32 + lg*8);
  }

  auto stage = [&](int buf, int kt){
    #pragma unroll
    for (int c=0;c<2;c++){          // A: act0 tile 64x64 (8KB), 128B rows
      uint lin = (uint)tid*16u + (uint)c*4096u;
      uint row = lin>>7, scol = (lin&127u) ^ (((lin>>7)&7u)<<4);
      gload_lds16((const char*)act0 + (((size_t)(bm+row)*512 + (uint)kt*64u)<<1) + scol,
                  smem + (buf?8192:0) + lin);
    }
    #pragma unroll
    for (int c=0;c<8;c++){          // B: W1t tile 256x64 (32KB), 128B rows
      uint lin = (uint)tid*16u + (uint)c*4096u;
      uint row = lin>>7, scol = (lin&127u) ^ (((lin>>7)&7u)<<4);
      gload_lds16((const char*)W1t + (((size_t)row*512 + (uint)kt*64u)<<1) + scol,
                  smem + 16384 + (buf?32768:0) + lin);
    }
  };

  f32x4 acc[4][4];
  #pragma unroll
  for (int m=0;m<4;m++)
    #pragma unroll
    for (int n=0;n<4;n++)
      #pragma unroll
      for (int j=0;j<4;j++) acc[m][n][j] = 0.f;

  stage(0,0);
  int cur = 0;
  for (int t=0;t<8;t++){
    stage(cur^1, (t+1<8) ? t+1 : 0);   // dead tail stage keeps vmcnt uniform
    asm volatile("s_waitcnt vmcnt(10)" ::: "memory");
    __builtin_amdgcn_s_barrier();
    asm volatile("" ::: "memory");
    const char* lAc = smem + (cur?8192:0);
    const char* lBc = smem + 16384 + (cur?32768:0);
    #pragma unroll
    for (int kk2=0;kk2<2;kk2++){
      short8 af[4], bfr[4];
      #pragma unroll
      for (int m=0;m<4;m++){
        uint row = (uint)(m*16+lr);
        uint l = row*128u + (uint)kk2*64u + (uint)lg*16u;
        af[m] = *(const short8*)(lAc + (l ^ ((row&7u)<<4)));
      }
      #pragma unroll
      for (int n=0;n<4;n++){
        uint row = (uint)(wave*64 + n*16+lr);
        uint l = row*128u + (uint)kk2*64u + (uint)lg*16u;
        bfr[n] = *(const short8*)(lBc + (l ^ ((row&7u)<<4)));
      }
      #pragma unroll
      for (int m=0;m<4;m++)
        #pragma unroll
        for (int n=0;n<4;n++)
          acc[m][n] = __builtin_amdgcn_mfma_f32_16x16x32_bf16(af[m], bfr[n], acc[m][n], 0,0,0);
    }
    asm volatile("" ::: "memory");
    __builtin_amdgcn_s_barrier();
    cur ^= 1;
  }
  asm volatile("s_waitcnt vmcnt(0)" ::: "memory");   // drain tail before LDS reuse
  __syncthreads();

  // act1 tile -> LDS (relu + b1), padded stride 264 ushorts
  ushort* a1 = (ushort*)smem;
  #pragma unroll
  for (int n=0;n<4;n++){
    int col = wave*64 + n*16 + lr;
    float bv = b1[col];
    #pragma unroll
    for (int m=0;m<4;m++)
      #pragma unroll
      for (int j=0;j<4;j++){
        int row = m*16 + lg*4 + j;
        a1[(uint)row*264u + (uint)col] = f2bf(fmaxf(acc[m][n][j] + bv, 0.f));
      }
  }
  __syncthreads();

  // phase 2: x(64x128) = act1(64x256) @ W2t(128x256)^T ; W2 from registers
  f32x4 acc2[4][2];
  #pragma unroll
  for (int m=0;m<4;m++)
    #pragma unroll
    for (int n=0;n<2;n++)
      #pragma unroll
      for (int j=0;j<4;j++) acc2[m][n][j] = 0.f;

  #pragma unroll
  for (int ks=0;ks<8;ks++){
    short8 af[4];
    #pragma unroll
    for (int m=0;m<4;m++)
      af[m] = *(const short8*)&a1[(uint)(m*16+lr)*264u + (uint)ks*32u + (uint)lg*8u];
    #pragma unroll
    for (int m=0;m<4;m++)
      #pragma unroll
      for (int n=0;n<2;n++)
        acc2[m][n] = __builtin_amdgcn_mfma_f32_16x16x32_bf16(af[m], w2r[n][ks], acc2[m][n], 0,0,0);
  }

  #pragma unroll
  for (int n=0;n<2;n++){
    int col = wave*32 + n*16 + lr;
    float bv = b2[col];
    #pragma unroll
    for (int m=0;m<4;m++)
      #pragma unroll
      for (int j=0;j<4;j++){
        int row = bm + m*16 + lg*4 + j;
        R[(size_t)row*512 + col] = f2bf(fmaxf(acc2[m][n][j] + bv, 0.f));
      }
  }
}

// ---------------- 256xBN deep-pipelined GEMM (8 phases / 2 K-tiles, counted vmcnt, swizzled LDS)
template<int BN, bool FUSE>
__global__ __launch_bounds__(512, 2) void gemm256(const ushort* __restrict__ A,
    const ushort* __restrict__ Bt, const float* __restrict__ bias,
    ushort* __restrict__ C, int K, int ldc,
    const float* __restrict__ w3, float* __restrict__ partial)
{
  constexpr int  NF = BN/128;
  constexpr int  LB = BN/128;
  constexpr uint BR = (uint)BN*32u;
  constexpr uint BUFSZ = 16384u + 2u*BR;
  __shared__ __align__(16) ushort lds[2*BUFSZ];

  const int tid = threadIdx.x;
  const int wave = tid>>6, lane = tid&63;
  const uint wm = (uint)(wave>>2), wn = (uint)(wave&3);
  const uint lc = (uint)(lane&31), hi = (uint)(lane>>5);
  const int bm = blockIdx.x*256, bn = blockIdx.y*BN;
  const int nt = K>>6, niter = nt>>1;

  f32x16 acc[4][NF];
  #pragma unroll
  for (int m=0;m<4;m++)
    #pragma unroll
    for (int n=0;n<NF;n++)
      #pragma unroll
      for (int j=0;j<16;j++) acc[m][n][j] = 0.f;

  short8 bfr[2][NF];

#define STAGE(MAT, KH, TILE, SBUF) do{                                          \
    int kt_ = (TILE);                                                           \
    int ktc_ = (kt_ < nt) ? kt_ : 0;                                            \
    const ushort* gb_ = (MAT) ? Bt : A;                                         \
    const uint ro_ = (MAT) ? (uint)bn : (uint)bm;                               \
    const uint rb_ = (uint)(SBUF)*BUFSZ + ((MAT) ? (16384u + (uint)(KH)*BR)     \
                                                 : ((uint)(KH)*8192u));         \
    const int nl_ = (MAT) ? LB : 2;                                             \
    _Pragma("unroll")                                                           \
    for (int j_=0; j_<nl_; ++j_){                                               \
      uint lin_ = (uint)tid*16u + (uint)j_*8192u;                               \
      uint src_ = lin_ ^ (((lin_>>7)&3u)<<4);                                   \
      uint row_ = src_>>6, colb_ = src_&63u;                                    \
      const char* g_ = (const char*)gb_ +                                       \
        (((size_t)(ro_+row_)*(size_t)K + (size_t)ktc_*64 + (KH)*32)<<1) + colb_;\
      gload_lds16(g_, (char*)lds + (size_t)rb_*2 + lin_);                       \
    }                                                                           \
  }while(0)

#define PHASE(CBUF, KKH, MH, BLOAD, SMAT, SKH, STILE, SBUF, CKPT) do{           \
    const uint ab_ = (uint)(CBUF)*BUFSZ + (uint)(KKH)*8192u;                    \
    short8 af_[2][2];                                                           \
    _Pragma("unroll")                                                           \
    for (int mfl_=0; mfl_<2; ++mfl_){                                           \
      uint r_ = wm*128u + ((uint)(MH)*2u+(uint)mfl_)*32u + lc;                  \
      _Pragma("unroll")                                                         \
      for (int k2_=0; k2_<2; ++k2_){                                            \
        uint l_ = r_*64u + hi*16u + (uint)k2_*32u;                              \
        af_[mfl_][k2_] = *(const short8*)((const char*)lds + (size_t)ab_*2      \
                                   + (l_ ^ (((l_>>7)&3u)<<4)));                 \
      }                                                                         \
    }                                                                           \
    if (BLOAD){                                                                 \
      const uint bb_ = (uint)(CBUF)*BUFSZ + 16384u + (uint)(KKH)*BR;            \
      _Pragma("unroll")                                                         \
      for (int nf_=0; nf_<NF; ++nf_){                                           \
        uint r_ = wn*(uint)(BN/4) + (uint)nf_*32u + lc;                         \
        _Pragma("unroll")                                                       \
        for (int k2_=0; k2_<2; ++k2_){                                          \
          uint l_ = r_*64u + hi*16u + (uint)k2_*32u;                            \
          bfr[k2_][nf_] = *(const short8*)((const char*)lds + (size_t)bb_*2     \
                                     + (l_ ^ (((l_>>7)&3u)<<4)));               \
        }                                                                       \
      }                                                                         \
    }                                                                           \
    STAGE(SMAT, SKH, STILE, SBUF);                                              \
    asm volatile("" ::: "memory");                                              \
    __builtin_amdgcn_s_barrier();                                               \
    asm volatile("" ::: "memory");                                              \
    __builtin_amdgcn_s_setprio(1);                                              \
    _Pragma("unroll")                                                           \
    for (int mfl_=0; mfl_<2; ++mfl_)                                            \
      _Pragma("unroll")                                                         \
      for (int nf_=0; nf_<NF; ++nf_)                                            \
        _Pragma("unroll")                                                       \
        for (int k2_=0; k2_<2; ++k2_)                                           \
          acc[(MH)*2+mfl_][nf_] = __builtin_amdgcn_mfma_f32_32x32x16_bf16(      \
              af_[mfl_][k2_], bfr[k2_][nf_], acc[(MH)*2+mfl_][nf_], 0,0,0);     \
    __builtin_amdgcn_s_setprio(0);                                              \
    if (CKPT){                                                                  \
      if constexpr (LB==2) asm volatile("s_waitcnt vmcnt(8)" ::: "memory");     \
      else                 asm volatile("s_waitcnt vmcnt(6)" ::: "memory");     \
    }                                                                           \
    asm volatile("" ::: "memory");                                              \
    __builtin_amdgcn_s_barrier();                                               \
  }while(0)

  STAGE(0,0,0,0); STAGE(1,0,0,0); STAGE(0,1,0,0); STAGE(1,1,0,0);
  STAGE(0,0,1,1); STAGE(1,0,1,1);
  if constexpr (LB==2) asm volatile("s_waitcnt vmcnt(4)" ::: "memory");
  else                 asm volatile("s_waitcnt vmcnt(3)" ::: "memory");
  asm volatile("" ::: "memory");
  __builtin_amdgcn_s_barrier();

  for (int i=0; i<niter; ++i){
    const int O  = 2*i+1;
    const int E2 = 2*i+2;
    const int O2 = 2*i+3;
    PHASE(0,0,0,true , 0,1,O ,1, false);
    PHASE(0,0,1,false, 1,1,O ,1, true );
    PHASE(0,1,0,true , 0,0,E2,0, false);
    PHASE(0,1,1,false, 1,0,E2,0, true );
    PHASE(1,0,0,true , 0,1,E2,0, false);
    PHASE(1,0,1,false, 1,1,E2,0, true );
    PHASE(1,1,0,true , 0,0,O2,1, false);
    PHASE(1,1,1,false, 1,0,O2,1, true );
  }
#undef PHASE
#undef STAGE

  if constexpr (FUSE){
    int col = bn + (int)wn*(BN/4) + (int)lc;
    float bv = bias[col];
    float wv = w3[col];
    #pragma unroll
    for (int mf=0; mf<4; ++mf){
      #pragma unroll
      for (int reg=0; reg<16; ++reg){
        float v = fmaxf(acc[mf][0][reg] + bv, 0.f) * wv;
        #pragma unroll
        for (int off=1; off<32; off<<=1) v += __shfl_xor(v, off);
        if (lc == 0){
          int row = bm + (int)wm*128 + mf*32 + (reg&3) + 8*(reg>>2) + 4*(int)hi;
          atomicAdd(&partial[row], v);
        }
      }
    }
  } else {
    #pragma unroll
    for (int nf=0; nf<NF; ++nf){
      int col = bn + (int)wn*(BN/4) + nf*32 + (int)lc;
      float bv = bias[col];
      #pragma unroll
      for (int mf=0; mf<4; ++mf){
        #pragma unroll
        for (int reg=0; reg<16; ++reg){
          int row = bm + (int)wm*128 + mf*32 + (reg&3) + 8*(reg>>2) + 4*(int)hi;
          float v = acc[mf][nf][reg] + bv;
          C[(size_t)row*ldc + col] = f2bf(fmaxf(v, 0.f));
        }
      }
    }
  }
}

// ---------------- embedding gather + pairwise interaction, in-place on R (B x 512 bf16)
__global__ __launch_bounds__(256) void interact(const int* __restrict__ idx,
    const float* __restrict__ emb, ushort* __restrict__ R)
{
  __shared__ __align__(16) ushort Tl[4][32][136];
  const int w = threadIdx.x>>6, l = threadIdx.x&63;
  const int b = blockIdx.x*4 + w;
  ushort* Rrow = R + (size_t)b*512;

  uint xv = ((const uint*)Rrow)[l];
  *(uint*)&Tl[w][0][2*l] = xv;

  int myidx = (l<26) ? idx[(size_t)l*B_ROWS + b] : 0;
  const int half = l>>5, lc = l&31;
  #pragma unroll
  for (int i=0;i<13;i++){
    const int row = 2*i + 1 + half;
    int e = __shfl(myidx, row - 1);
    const float4* rp = (const float4*)(emb + ((size_t)(row-1)*50000 + (size_t)e)*128);
    float4 v = rp[lc];
    uint2 pk;
    pk.x = (uint)f2bf(v.x) | ((uint)f2bf(v.y)<<16);
    pk.y = (uint)f2bf(v.z) | ((uint)f2bf(v.w)<<16);
    *(uint2*)&Tl[w][row][4*lc] = pk;
  }
  __syncthreads();

  f32x16 acc;
  #pragma unroll
  for (int i=0;i<16;i++) acc[i] = 0.f;
  #pragma unroll
  for (int kk=0;kk<8;kk++){
    short8 fa = *(const short8*)((const char*)&Tl[w][0][0] + (size_t)(l&31)*272 + kk*32 + (l>>5)*16);
    acc = __builtin_amdgcn_mfma_f32_32x32x16_bf16(fa, fa, acc, 0,0,0);
  }

  const int c = l&31;
  #pragma unroll
  for (int j=0;j<16;j++){
    int r = (j&3) + 8*(j>>2) + 4*(l>>5);
    if (c < r && r <= 26) Rrow[128 + r*(r-1)/2 + c] = f2bf(acc[j]);
  }
  if (l < 33) Rrow[479 + l] = 0;
}

// ---------------- final: sigmoid(partial + b3), clip -> fp32 out
__global__ __launch_bounds__(256) void sigm(const float* __restrict__ partial,
    const float* __restrict__ b3, float* __restrict__ out)
{
  int i = blockIdx.x*256 + threadIdx.x;
  float h = partial[i] + b3[0];
  float p = 1.f/(1.f + expf(-h));
  out[i] = fminf(fmaxf(p, 0.f), 1.f);
}

extern "C" void kernel_launch(void* const* d_in, const int* in_sizes, int n_in,
                              void* d_out, int out_size, void* d_ws, size_t ws_size,
                              hipStream_t stream)
{
  const float* dense_x = (const float*)d_in[0];
  const int*   indices = (const int*)d_in[1];
  const float* emb     = (const float*)d_in[2];
  const float* bW0 = (const float*)d_in[3];  const float* bb0 = (const float*)d_in[4];
  const float* bW1 = (const float*)d_in[5];  const float* bb1 = (const float*)d_in[6];
  const float* bW2 = (const float*)d_in[7];  const float* bb2 = (const float*)d_in[8];
  const float* tW0 = (const float*)d_in[9];  const float* tb0 = (const float*)d_in[10];
  const float* tW1 = (const float*)d_in[11]; const float* tb1 = (const float*)d_in[12];
  const float* tW2 = (const float*)d_in[13]; const float* tb2 = (const float*)d_in[14];
  const float* tW3 = (const float*)d_in[15]; const float* tb3 = (const float*)d_in[16];
  float* out = (float*)d_out;
  const int Bn = B_ROWS;

  char* ws = (char*)d_ws;
  size_t o = 0;
  auto alloc = [&](size_t bytes)->char*{ char* r = ws + o; o += (bytes + 255) & ~(size_t)255; return r; };
  ushort* wtB1 = (ushort*)alloc(256*512*2);
  ushort* wtB2 = (ushort*)alloc(128*256*2);
  ushort* wtT0 = (ushort*)alloc(1024*512*2);
  ushort* wtT1 = (ushort*)alloc((size_t)1024*1024*2);
  ushort* wtT2 = (ushort*)alloc(512*1024*2);
  float*  partial = (float*)alloc(B_ROWS*4);
  ushort* P    = (ushort*)alloc((size_t)Bn*512*2);
  ushort* h1   = (ushort*)alloc((size_t)Bn*1024*2);
  ushort* h2   = (ushort*)alloc((size_t)Bn*1024*2);
  (void)ws_size; (void)in_sizes; (void)n_in; (void)out_size;

  // combined prep: bot0 + weight transposes + partial zeroing
  PrepArgs pa;
  pa.x = dense_x; pa.W0 = bW0; pa.b0 = bb0; pa.act0 = P;
  pa.t[0] = { bW1, wtB1, 512 , 256 , 512  };
  pa.t[1] = { bW2, wtB2, 256 , 128 , 256  };
  pa.t[2] = { tW0, wtT0, 479 , 1024, 512  };
  pa.t[3] = { tW1, wtT1, 1024, 1024, 1024 };
  pa.t[4] = { tW2, wtT2, 1024, 512 , 1024 };
  pa.partial = partial;
  prep<<<35040,256,0,stream>>>(pa);

  // fused bottom layers 1+2 (act1 LDS-only; x into R cols [0,128)); 2 blocks/CU
  bot12<<<256,256,0,stream>>>(P, wtB1, bb1, wtB2, bb2, P);

  // gather + interaction in place on R (= P)
  interact<<<Bn/4,256,0,stream>>>(indices, emb, P);

  // top MLP: deep-pipelined 256-tile GEMMs (32x32x16 MFMA); top2 fuses the final dot
  gemm256<256,false><<<dim3(64,4),512,0,stream>>>(P,  wtT0, tb0, h1, 512 , 1024, nullptr, nullptr);
  gemm256<256,false><<<dim3(64,4),512,0,stream>>>(h1, wtT1, tb1, h2, 1024, 1024, nullptr, nullptr);
  gemm256<128,true ><<<dim3(64,4),512,0,stream>>>(h2, wtT2, tb2, nullptr, 1024, 0, tW3, partial);
  sigm<<<Bn/256,256,0,stream>>>(partial, tb3, out);
}

// Round 12
// 168.199 us; speedup vs baseline: 1.2667x; 1.1024x over previous
//
#include <hip/hip_runtime.h>

typedef __attribute__((ext_vector_type(8))) short short8;
typedef __attribute__((ext_vector_type(4))) float f32x4;
typedef __attribute__((ext_vector_type(16))) float f32x16;

#define B_ROWS 16384

__device__ __forceinline__ float bf2f(ushort u){ return __uint_as_float(((uint)u)<<16); }
__device__ __forceinline__ ushort f2bf(float f){
  uint u = __float_as_uint(f);
  u = u + 0x7FFFu + ((u>>16)&1u);
  return (ushort)(u>>16);
}
__device__ __forceinline__ void gload_lds16(const void* g, void* l){
  __builtin_amdgcn_global_load_lds((const __attribute__((address_space(1))) unsigned*)g,
                                   (__attribute__((address_space(3))) unsigned*)l, 16, 0, 0);
}

// ---------------- prep kernel: 5 weight transposes + partial-zero (bot0 now fused into bot012)
// grid: [0,2208) transpose tiles; [2208,2272) zero partial
struct TArgs { const float* in; ushort* out; int K, N, Kp; };
struct PrepArgs { TArgs t[5]; float* partial; };

__global__ __launch_bounds__(256) void prep(PrepArgs a)
{
  const int idx = blockIdx.x;
  const int tid = threadIdx.x;
  __shared__ float tile[32][33];

  if (idx >= 2208){                       // ---- zero the final-layer partial buffer
    a.partial[(idx-2208)*256 + tid] = 0.f;
    return;
  }
  // ---- transpose tiles: bW1(16x8), bW2(8x4), tW0(16x32), tW1(32x32), tW2(32x16)
  int t = idx, s, kx, ny;
  if (t < 128)              { s=0; kx=t&15; ny=t>>4; }
  else if ((t-=128) < 32)   { s=1; kx=t&7 ; ny=t>>3; }
  else if ((t-=32) < 512)   { s=2; kx=t&15; ny=t>>4; }
  else if ((t-=512) < 1024) { s=3; kx=t&31; ny=t>>5; }
  else { t-=1024;             s=4; kx=t&31; ny=t>>5; }
  TArgs ta = a.t[s];
  int k0 = kx*32, n0 = ny*32;
  const int c = tid & 31, r8 = tid >> 5;
  #pragma unroll
  for (int p=0;p<4;p++){
    int k = k0 + r8 + p*8;
    tile[r8+p*8][c] = (k < ta.K) ? ta.in[(size_t)k*ta.N + n0 + c] : 0.f;
  }
  __syncthreads();
  #pragma unroll
  for (int p=0;p<4;p++){
    int n = n0 + r8 + p*8;
    ta.out[(size_t)n*ta.Kp + k0 + c] = f2bf(tile[c][r8+p*8]);
  }
}

// ---------------- fused bottom MLP (all 3 layers): x(64x13) -> act0(64x512, computed in LDS)
// -> @W1t^T -> act1(64x256, LDS) -> @W2t^T (regs) -> xout(64x128) into R cols [0,128).
// 64-row blocks, 4 waves. act0 write/read swizzle ^((r&7)<<4); W1t staging as before.
__global__ __launch_bounds__(256) void bot012(const float* __restrict__ x,
    const float* __restrict__ W0, const float* __restrict__ b0,
    const ushort* __restrict__ W1t, const float* __restrict__ b1,
    const ushort* __restrict__ W2t, const float* __restrict__ b2,
    ushort* __restrict__ R)
{
  // LDS map (bytes): W0f [0,26624) ; xf [26624,30720) (rows padded to 16 floats)
  // act0 [30720,96256) 64KB bf16 swizzled ; lB[2] [96256,161792) 2x32KB
  // a1 (64x264 ushorts = 33792B) reuses act0 region after phase-1.
  __shared__ __align__(16) char smem[161792];
  float* W0f = (float*)smem;
  float* xf  = (float*)(smem + 26624);
  char*  act0 = smem + 30720;
  const int tid = threadIdx.x;
  const int wave = tid>>6, lane = tid&63;
  const int lr = lane&15, lg = lane>>4;
  const int bm = blockIdx.x*64;

  // fill W0 (13x512 fp32) and x tile (64 rows padded to 16) into LDS
  for (int i2=tid; i2<6656; i2+=256) W0f[i2] = W0[i2];
  for (int i2=tid; i2<1024; i2+=256){
    int r = i2>>4, c = i2&15;
    xf[i2] = (c<13) ? x[((size_t)(bm+r))*13 + c] : 0.f;
  }

  // W2 fragments to registers (L2-hot; drained by first __syncthreads)
  short8 w2r[2][8];
  #pragma unroll
  for (int n=0;n<2;n++){
    int row = wave*32 + n*16 + lr;
    #pragma unroll
    for (int ks=0;ks<8;ks++)
      w2r[n][ks] = *(const short8*)(W2t + (size_t)row*256 + ks*32 + lg*8);
  }

  auto stageB = [&](int buf, int kt){
    #pragma unroll
    for (int c=0;c<8;c++){          // W1t tile 256x64 (32KB), 128B rows, swizzled source
      uint lin = (uint)tid*16u + (uint)c*4096u;
      uint row = lin>>7, scol = (lin&127u) ^ (((lin>>7)&7u)<<4);
      gload_lds16((const char*)W1t + (((size_t)row*512 + (uint)kt*64u)<<1) + scol,
                  smem + 96256 + (buf?32768:0) + lin);
    }
  };

  __syncthreads();                  // W0f/xf visible
  stageB(0,0);                      // overlap first B-stage with act0 compute

  // ---- compute act0 = relu(x @ W0 + b0): thread -> cols {2*tid, 2*tid+1}, all 64 rows
  {
    float2 w0c[13];
    #pragma unroll
    for (int k=0;k<13;k++) w0c[k] = *(const float2*)&W0f[k*512 + 2*tid];
    float2 b0v = *(const float2*)&b0[2*tid];
    #pragma unroll 4
    for (int r=0;r<64;r++){
      float4 x0 = *(const float4*)&xf[r*16];
      float4 x1 = *(const float4*)&xf[r*16+4];
      float4 x2 = *(const float4*)&xf[r*16+8];
      float  xc = xf[r*16+12];
      float sA = b0v.x, sB = b0v.y;
      sA += x0.x*w0c[0].x + x0.y*w0c[1].x + x0.z*w0c[2].x + x0.w*w0c[3].x;
      sB += x0.x*w0c[0].y + x0.y*w0c[1].y + x0.z*w0c[2].y + x0.w*w0c[3].y;
      sA += x1.x*w0c[4].x + x1.y*w0c[5].x + x1.z*w0c[6].x + x1.w*w0c[7].x;
      sB += x1.x*w0c[4].y + x1.y*w0c[5].y + x1.z*w0c[6].y + x1.w*w0c[7].y;
      sA += x2.x*w0c[8].x + x2.y*w0c[9].x + x2.z*w0c[10].x + x2.w*w0c[11].x;
      sB += x2.x*w0c[8].y + x2.y*w0c[9].y + x2.z*w0c[10].y + x2.w*w0c[11].y;
      sA += xc*w0c[12].x;  sB += xc*w0c[12].y;
      uint pk = (uint)f2bf(fmaxf(sA,0.f)) | ((uint)f2bf(fmaxf(sB,0.f))<<16);
      uint a0 = (uint)r*1024u + (uint)tid*4u;
      *(uint*)(act0 + (a0 ^ (((uint)(r&7))<<4))) = pk;
    }
  }
  __syncthreads();                  // act0 visible (also drains stage(0) — harmless)

  // ---- phase 1: act1 = relu(act0 @ W1t^T + b1); A from act0-LDS, B double-buffered
  f32x4 acc[4][4];
  #pragma unroll
  for (int m=0;m<4;m++)
    #pragma unroll
    for (int n=0;n<4;n++)
      #pragma unroll
      for (int j=0;j<4;j++) acc[m][n][j] = 0.f;

  int cur = 0;
  for (int t=0;t<8;t++){
    stageB(cur^1, (t+1<8) ? t+1 : 0);   // dead tail stage keeps vmcnt uniform
    asm volatile("s_waitcnt vmcnt(8)" ::: "memory");
    __builtin_amdgcn_s_barrier();
    asm volatile("" ::: "memory");
    const char* lBc = smem + 96256 + (cur?32768:0);
    #pragma unroll
    for (int kk2=0;kk2<2;kk2++){
      short8 af[4], bfr[4];
      #pragma unroll
      for (int m=0;m<4;m++){
        uint a0 = (uint)(m*16+lr)*1024u + (uint)t*128u + (uint)kk2*64u + (uint)lg*16u;
        af[m] = *(const short8*)(act0 + (a0 ^ (((uint)(lr&7))<<4)));
      }
      #pragma unroll
      for (int n=0;n<4;n++){
        uint row = (uint)(wave*64 + n*16+lr);
        uint l = row*128u + (uint)kk2*64u + (uint)lg*16u;
        bfr[n] = *(const short8*)(lBc + (l ^ ((row&7u)<<4)));
      }
      #pragma unroll
      for (int m=0;m<4;m++)
        #pragma unroll
        for (int n=0;n<4;n++)
          acc[m][n] = __builtin_amdgcn_mfma_f32_16x16x32_bf16(af[m], bfr[n], acc[m][n], 0,0,0);
    }
    asm volatile("" ::: "memory");
    __builtin_amdgcn_s_barrier();
    cur ^= 1;
  }
  asm volatile("s_waitcnt vmcnt(0)" ::: "memory");   // drain dead tail stage
  __syncthreads();

  // act1 tile -> LDS (relu + b1), padded stride 264 ushorts (reuses act0 region)
  ushort* a1 = (ushort*)(smem + 30720);
  #pragma unroll
  for (int n=0;n<4;n++){
    int col = wave*64 + n*16 + lr;
    float bv = b1[col];
    #pragma unroll
    for (int m=0;m<4;m++)
      #pragma unroll
      for (int j=0;j<4;j++){
        int row = m*16 + lg*4 + j;
        a1[(uint)row*264u + (uint)col] = f2bf(fmaxf(acc[m][n][j] + bv, 0.f));
      }
  }
  __syncthreads();

  // phase 2: xout(64x128) = act1(64x256) @ W2t(128x256)^T ; W2 from registers
  f32x4 acc2[4][2];
  #pragma unroll
  for (int m=0;m<4;m++)
    #pragma unroll
    for (int n=0;n<2;n++)
      #pragma unroll
      for (int j=0;j<4;j++) acc2[m][n][j] = 0.f;

  #pragma unroll
  for (int ks=0;ks<8;ks++){
    short8 af[4];
    #pragma unroll
    for (int m=0;m<4;m++)
      af[m] = *(const short8*)&a1[(uint)(m*16+lr)*264u + (uint)ks*32u + (uint)lg*8u];
    #pragma unroll
    for (int m=0;m<4;m++)
      #pragma unroll
      for (int n=0;n<2;n++)
        acc2[m][n] = __builtin_amdgcn_mfma_f32_16x16x32_bf16(af[m], w2r[n][ks], acc2[m][n], 0,0,0);
  }

  #pragma unroll
  for (int n=0;n<2;n++){
    int col = wave*32 + n*16 + lr;
    float bv = b2[col];
    #pragma unroll
    for (int m=0;m<4;m++)
      #pragma unroll
      for (int j=0;j<4;j++){
        int row = bm + m*16 + lg*4 + j;
        R[(size_t)row*512 + col] = f2bf(fmaxf(acc2[m][n][j] + bv, 0.f));
      }
  }
}

// ---------------- 256xBN deep-pipelined GEMM (8 phases / 2 K-tiles, counted vmcnt, swizzled LDS)
template<int BN, bool FUSE>
__global__ __launch_bounds__(512, 2) void gemm256(const ushort* __restrict__ A,
    const ushort* __restrict__ Bt, const float* __restrict__ bias,
    ushort* __restrict__ C, int K, int ldc,
    const float* __restrict__ w3, float* __restrict__ partial)
{
  constexpr int  NF = BN/128;
  constexpr int  LB = BN/128;
  constexpr uint BR = (uint)BN*32u;
  constexpr uint BUFSZ = 16384u + 2u*BR;
  __shared__ __align__(16) ushort lds[2*BUFSZ];

  const int tid = threadIdx.x;
  const int wave = tid>>6, lane = tid&63;
  const uint wm = (uint)(wave>>2), wn = (uint)(wave&3);
  const uint lc = (uint)(lane&31), hi = (uint)(lane>>5);
  const int bm = blockIdx.x*256, bn = blockIdx.y*BN;
  const int nt = K>>6, niter = nt>>1;

  f32x16 acc[4][NF];
  #pragma unroll
  for (int m=0;m<4;m++)
    #pragma unroll
    for (int n=0;n<NF;n++)
      #pragma unroll
      for (int j=0;j<16;j++) acc[m][n][j] = 0.f;

  short8 bfr[2][NF];

#define STAGE(MAT, KH, TILE, SBUF) do{                                          \
    int kt_ = (TILE);                                                           \
    int ktc_ = (kt_ < nt) ? kt_ : 0;                                            \
    const ushort* gb_ = (MAT) ? Bt : A;                                         \
    const uint ro_ = (MAT) ? (uint)bn : (uint)bm;                               \
    const uint rb_ = (uint)(SBUF)*BUFSZ + ((MAT) ? (16384u + (uint)(KH)*BR)     \
                                                 : ((uint)(KH)*8192u));         \
    const int nl_ = (MAT) ? LB : 2;                                             \
    _Pragma("unroll")                                                           \
    for (int j_=0; j_<nl_; ++j_){                                               \
      uint lin_ = (uint)tid*16u + (uint)j_*8192u;                               \
      uint src_ = lin_ ^ (((lin_>>7)&3u)<<4);                                   \
      uint row_ = src_>>6, colb_ = src_&63u;                                    \
      const char* g_ = (const char*)gb_ +                                       \
        (((size_t)(ro_+row_)*(size_t)K + (size_t)ktc_*64 + (KH)*32)<<1) + colb_;\
      gload_lds16(g_, (char*)lds + (size_t)rb_*2 + lin_);                       \
    }                                                                           \
  }while(0)

#define PHASE(CBUF, KKH, MH, BLOAD, SMAT, SKH, STILE, SBUF, CKPT) do{           \
    const uint ab_ = (uint)(CBUF)*BUFSZ + (uint)(KKH)*8192u;                    \
    short8 af_[2][2];                                                           \
    _Pragma("unroll")                                                           \
    for (int mfl_=0; mfl_<2; ++mfl_){                                           \
      uint r_ = wm*128u + ((uint)(MH)*2u+(uint)mfl_)*32u + lc;                  \
      _Pragma("unroll")                                                         \
      for (int k2_=0; k2_<2; ++k2_){                                            \
        uint l_ = r_*64u + hi*16u + (uint)k2_*32u;                              \
        af_[mfl_][k2_] = *(const short8*)((const char*)lds + (size_t)ab_*2      \
                                   + (l_ ^ (((l_>>7)&3u)<<4)));                 \
      }                                                                         \
    }                                                                           \
    if (BLOAD){                                                                 \
      const uint bb_ = (uint)(CBUF)*BUFSZ + 16384u + (uint)(KKH)*BR;            \
      _Pragma("unroll")                                                         \
      for (int nf_=0; nf_<NF; ++nf_){                                           \
        uint r_ = wn*(uint)(BN/4) + (uint)nf_*32u + lc;                         \
        _Pragma("unroll")                                                       \
        for (int k2_=0; k2_<2; ++k2_){                                          \
          uint l_ = r_*64u + hi*16u + (uint)k2_*32u;                            \
          bfr[k2_][nf_] = *(const short8*)((const char*)lds + (size_t)bb_*2     \
                                     + (l_ ^ (((l_>>7)&3u)<<4)));               \
        }                                                                       \
      }                                                                         \
    }                                                                           \
    STAGE(SMAT, SKH, STILE, SBUF);                                              \
    asm volatile("" ::: "memory");                                              \
    __builtin_amdgcn_s_barrier();                                               \
    asm volatile("" ::: "memory");                                              \
    __builtin_amdgcn_s_setprio(1);                                              \
    _Pragma("unroll")                                                           \
    for (int mfl_=0; mfl_<2; ++mfl_)                                            \
      _Pragma("unroll")                                                         \
      for (int nf_=0; nf_<NF; ++nf_)                                            \
        _Pragma("unroll")                                                       \
        for (int k2_=0; k2_<2; ++k2_)                                           \
          acc[(MH)*2+mfl_][nf_] = __builtin_amdgcn_mfma_f32_32x32x16_bf16(      \
              af_[mfl_][k2_], bfr[k2_][nf_], acc[(MH)*2+mfl_][nf_], 0,0,0);     \
    __builtin_amdgcn_s_setprio(0);                                              \
    if (CKPT){                                                                  \
      if constexpr (LB==2) asm volatile("s_waitcnt vmcnt(8)" ::: "memory");     \
      else                 asm volatile("s_waitcnt vmcnt(6)" ::: "memory");     \
    }                                                                           \
    asm volatile("" ::: "memory");                                              \
    __builtin_amdgcn_s_barrier();                                               \
  }while(0)

  STAGE(0,0,0,0); STAGE(1,0,0,0); STAGE(0,1,0,0); STAGE(1,1,0,0);
  STAGE(0,0,1,1); STAGE(1,0,1,1);
  if constexpr (LB==2) asm volatile("s_waitcnt vmcnt(4)" ::: "memory");
  else                 asm volatile("s_waitcnt vmcnt(3)" ::: "memory");
  asm volatile("" ::: "memory");
  __builtin_amdgcn_s_barrier();

  for (int i=0; i<niter; ++i){
    const int O  = 2*i+1;
    const int E2 = 2*i+2;
    const int O2 = 2*i+3;
    PHASE(0,0,0,true , 0,1,O ,1, false);
    PHASE(0,0,1,false, 1,1,O ,1, true );
    PHASE(0,1,0,true , 0,0,E2,0, false);
    PHASE(0,1,1,false, 1,0,E2,0, true );
    PHASE(1,0,0,true , 0,1,E2,0, false);
    PHASE(1,0,1,false, 1,1,E2,0, true );
    PHASE(1,1,0,true , 0,0,O2,1, false);
    PHASE(1,1,1,false, 1,0,O2,1, true );
  }
#undef PHASE
#undef STAGE

  if constexpr (FUSE){
    int col = bn + (int)wn*(BN/4) + (int)lc;
    float bv = bias[col];
    float wv = w3[col];
    #pragma unroll
    for (int mf=0; mf<4; ++mf){
      #pragma unroll
      for (int reg=0; reg<16; ++reg){
        float v = fmaxf(acc[mf][0][reg] + bv, 0.f) * wv;
        #pragma unroll
        for (int off=1; off<32; off<<=1) v += __shfl_xor(v, off);
        if (lc == 0){
          int row = bm + (int)wm*128 + mf*32 + (reg&3) + 8*(reg>>2) + 4*(int)hi;
          atomicAdd(&partial[row], v);
        }
      }
    }
  } else {
    #pragma unroll
    for (int nf=0; nf<NF; ++nf){
      int col = bn + (int)wn*(BN/4) + nf*32 + (int)lc;
      float bv = bias[col];
      #pragma unroll
      for (int mf=0; mf<4; ++mf){
        #pragma unroll
        for (int reg=0; reg<16; ++reg){
          int row = bm + (int)wm*128 + mf*32 + (reg&3) + 8*(reg>>2) + 4*(int)hi;
          float v = acc[mf][nf][reg] + bv;
          C[(size_t)row*ldc + col] = f2bf(fmaxf(v, 0.f));
        }
      }
    }
  }
}

// ---------------- embedding gather + pairwise interaction, in-place on R (B x 512 bf16)
__global__ __launch_bounds__(256) void interact(const int* __restrict__ idx,
    const float* __restrict__ emb, ushort* __restrict__ R)
{
  __shared__ __align__(16) ushort Tl[4][32][136];
  const int w = threadIdx.x>>6, l = threadIdx.x&63;
  const int b = blockIdx.x*4 + w;
  ushort* Rrow = R + (size_t)b*512;

  uint xv = ((const uint*)Rrow)[l];
  *(uint*)&Tl[w][0][2*l] = xv;

  int myidx = (l<26) ? idx[(size_t)l*B_ROWS + b] : 0;
  const int half = l>>5, lc = l&31;
  #pragma unroll
  for (int i=0;i<13;i++){
    const int row = 2*i + 1 + half;
    int e = __shfl(myidx, row - 1);
    const float4* rp = (const float4*)(emb + ((size_t)(row-1)*50000 + (size_t)e)*128);
    float4 v = rp[lc];
    uint2 pk;
    pk.x = (uint)f2bf(v.x) | ((uint)f2bf(v.y)<<16);
    pk.y = (uint)f2bf(v.z) | ((uint)f2bf(v.w)<<16);
    *(uint2*)&Tl[w][row][4*lc] = pk;
  }
  __syncthreads();

  f32x16 acc;
  #pragma unroll
  for (int i=0;i<16;i++) acc[i] = 0.f;
  #pragma unroll
  for (int kk=0;kk<8;kk++){
    short8 fa = *(const short8*)((const char*)&Tl[w][0][0] + (size_t)(l&31)*272 + kk*32 + (l>>5)*16);
    acc = __builtin_amdgcn_mfma_f32_32x32x16_bf16(fa, fa, acc, 0,0,0);
  }

  const int c = l&31;
  #pragma unroll
  for (int j=0;j<16;j++){
    int r = (j&3) + 8*(j>>2) + 4*(l>>5);
    if (c < r && r <= 26) Rrow[128 + r*(r-1)/2 + c] = f2bf(acc[j]);
  }
  if (l < 33) Rrow[479 + l] = 0;
}

// ---------------- final: sigmoid(partial + b3), clip -> fp32 out
__global__ __launch_bounds__(256) void sigm(const float* __restrict__ partial,
    const float* __restrict__ b3, float* __restrict__ out)
{
  int i = blockIdx.x*256 + threadIdx.x;
  float h = partial[i] + b3[0];
  float p = 1.f/(1.f + expf(-h));
  out[i] = fminf(fmaxf(p, 0.f), 1.f);
}

extern "C" void kernel_launch(void* const* d_in, const int* in_sizes, int n_in,
                              void* d_out, int out_size, void* d_ws, size_t ws_size,
                              hipStream_t stream)
{
  const float* dense_x = (const float*)d_in[0];
  const int*   indices = (const int*)d_in[1];
  const float* emb     = (const float*)d_in[2];
  const float* bW0 = (const float*)d_in[3];  const float* bb0 = (const float*)d_in[4];
  const float* bW1 = (const float*)d_in[5];  const float* bb1 = (const float*)d_in[6];
  const float* bW2 = (const float*)d_in[7];  const float* bb2 = (const float*)d_in[8];
  const float* tW0 = (const float*)d_in[9];  const float* tb0 = (const float*)d_in[10];
  const float* tW1 = (const float*)d_in[11]; const float* tb1 = (const float*)d_in[12];
  const float* tW2 = (const float*)d_in[13]; const float* tb2 = (const float*)d_in[14];
  const float* tW3 = (const float*)d_in[15]; const float* tb3 = (const float*)d_in[16];
  float* out = (float*)d_out;
  const int Bn = B_ROWS;

  char* ws = (char*)d_ws;
  size_t o = 0;
  auto alloc = [&](size_t bytes)->char*{ char* r = ws + o; o += (bytes + 255) & ~(size_t)255; return r; };
  ushort* wtB1 = (ushort*)alloc(256*512*2);
  ushort* wtB2 = (ushort*)alloc(128*256*2);
  ushort* wtT0 = (ushort*)alloc(1024*512*2);
  ushort* wtT1 = (ushort*)alloc((size_t)1024*1024*2);
  ushort* wtT2 = (ushort*)alloc(512*1024*2);
  float*  partial = (float*)alloc(B_ROWS*4);
  ushort* P    = (ushort*)alloc((size_t)Bn*512*2);
  ushort* h1   = (ushort*)alloc((size_t)Bn*1024*2);
  ushort* h2   = (ushort*)alloc((size_t)Bn*1024*2);
  (void)ws_size; (void)in_sizes; (void)n_in; (void)out_size;

  // prep: weight transposes + partial zeroing (bot0 fused into bot012)
  PrepArgs pa;
  pa.t[0] = { bW1, wtB1, 512 , 256 , 512  };
  pa.t[1] = { bW2, wtB2, 256 , 128 , 256  };
  pa.t[2] = { tW0, wtT0, 479 , 1024, 512  };
  pa.t[3] = { tW1, wtT1, 1024, 1024, 1024 };
  pa.t[4] = { tW2, wtT2, 1024, 512 , 1024 };
  pa.partial = partial;
  prep<<<2272,256,0,stream>>>(pa);

  // fused bottom MLP (bot0+bot1+bot2; act0/act1 LDS-only; x into R cols [0,128))
  bot012<<<256,256,0,stream>>>(dense_x, bW0, bb0, wtB1, bb1, wtB2, bb2, P);

  // gather + interaction in place on R (= P)
  interact<<<Bn/4,256,0,stream>>>(indices, emb, P);

  // top MLP: deep-pipelined 256-tile GEMMs (32x32x16 MFMA); top2 fuses the final dot
  gemm256<256,false><<<dim3(64,4),512,0,stream>>>(P,  wtT0, tb0, h1, 512 , 1024, nullptr, nullptr);
  gemm256<256,false><<<dim3(64,4),512,0,stream>>>(h1, wtT1, tb1, h2, 1024, 1024, nullptr, nullptr);
  gemm256<128,true ><<<dim3(64,4),512,0,stream>>>(h2, wtT2, tb2, nullptr, 1024, 0, tW3, partial);
  sigm<<<Bn/256,256,0,stream>>>(partial, tb3, out);
}